// Round 1
// 364.524 us; speedup vs baseline: 1.0733x; 1.0733x over previous
//
#include <hip/hip_runtime.h>

#define MT 16384   // B*T = 8*2048
#define NT 2048    // OUT
#define KT 2048    // IN
#define BM 256
#define BN 256
#define BK 64
#define NKT (KT / BK)    // 32 K-tiles
#define THREADS 512

typedef __attribute__((ext_vector_type(8))) short short8;     // 8 bf16 (4 VGPRs) MFMA A/B frag
typedef __attribute__((ext_vector_type(4))) float f32x4;      // MFMA C/D frag
typedef __attribute__((ext_vector_type(8))) unsigned short ushort8;
typedef __attribute__((ext_vector_type(4))) unsigned short ushort4v;

__device__ __forceinline__ unsigned short f32_bf16(float f) {
    union { float f; unsigned u; } v; v.f = f;
    return (unsigned short)((v.u + 0x7FFFu + ((v.u >> 16) & 1u)) >> 16);
}

// ---- merged preconvert: x (fp32->bf16) then w (int32->bf16), one dispatch ----

__global__ __launch_bounds__(256) void cvt_kernel(const float* __restrict__ x,
                                                  const int* __restrict__ w,
                                                  unsigned short* __restrict__ xb,
                                                  unsigned short* __restrict__ wb) {
    const int b = blockIdx.x;
    if (b < MT * KT / 2048) {
        size_t i = ((size_t)b * 256 + threadIdx.x) * 8;
        float4 v0 = *(const float4*)(x + i);
        float4 v1 = *(const float4*)(x + i + 4);
        ushort8 o;
        o[0] = f32_bf16(v0.x); o[1] = f32_bf16(v0.y); o[2] = f32_bf16(v0.z); o[3] = f32_bf16(v0.w);
        o[4] = f32_bf16(v1.x); o[5] = f32_bf16(v1.y); o[6] = f32_bf16(v1.z); o[7] = f32_bf16(v1.w);
        *(ushort8*)(xb + i) = o;
    } else {
        size_t i = ((size_t)(b - MT * KT / 2048) * 256 + threadIdx.x) * 8;
        int4 v0 = *(const int4*)(w + i);
        int4 v1 = *(const int4*)(w + i + 4);
        ushort8 o;
        o[0] = f32_bf16((float)v0.x); o[1] = f32_bf16((float)v0.y);
        o[2] = f32_bf16((float)v0.z); o[3] = f32_bf16((float)v0.w);
        o[4] = f32_bf16((float)v1.x); o[5] = f32_bf16((float)v1.y);
        o[6] = f32_bf16((float)v1.z); o[7] = f32_bf16((float)v1.w);
        *(ushort8*)(wb + i) = o;
    }
}

// ---- R7: 256x256 8-phase GEMM (T2+T3+T4+T5), C = A * W^T, epilogue *2^s + bias ----
//
// 8 waves (2M x 4N), per-wave 128x64 output = 8 M-frags x 4 N-frags of 16x16.
// M mapping INTERLEAVED: wave wm owns 16-row blocks {2f+wm} -> phase p of a
// K-tile computes blocks {4p+wm, 4p+2+wm}; phases 1-2 touch only A rows 0-127
// (half 0), 3-4 only 128-255 (half 1). B is read entirely at phase 1. This
// gives the half-tile free schedule: B-buf free after ph1, A-h0 after ph2,
// A-h1 after ph4 -> one-half-tile-per-phase stage rotation is slot-safe:
//   ph1: A(t+1)h1 | ph2: B(t+2)h0 | ph3: A(t+2)h0 | ph4: B(t+2)h1 [vmcnt 6]
//   ph5: A(t+2)h1 | ph6: B(t+3)h0 | ph7: A(t+3)h0 | ph8: B(t+3)h1 [vmcnt 6]
// vmcnt(6) = 2 loads/half-tile x 3 half-tiles in flight; at each tile boundary
// the next tile's 4 halves are >=4 issues old => guaranteed landed. Raw
// s_barrier (no __syncthreads) so the compiler never drains vmcnt to 0.
// LDS: [2 buf][256 rows][8 chunks of 16B], rotation swizzle (R3: conflict==0):
// logical (row,c) at slot row*8 + ((c+row)&7); global_load_lds source is
// pre-swizzled so LDS dest stays linear (lane-contiguous), per m104/m173.

__global__ __launch_bounds__(THREADS, 2) void gemm_8ph(
    const unsigned short* __restrict__ Abf, const unsigned short* __restrict__ Bbf,
    const int* __restrict__ sexp, const float* __restrict__ bias,
    float* __restrict__ C)
{
    __shared__ unsigned short As[2 * 2048 * 8];   // 64 KB: [buf][256 rows][8 chunks][8 bf16]
    __shared__ unsigned short Bs[2 * 2048 * 8];   // 64 KB

    const int tid  = threadIdx.x;
    const int bn   = blockIdx.x;            // N block; bn == XCD id (8 exact): B-slab L2-resident
    const int bm   = blockIdx.y;
    const int brow0 = bm * BM;
    const int bcol0 = bn * BN;
    const int lane = tid & 63;
    const int wave = tid >> 6;
    const int wm = wave >> 2;               // 0..1  (M, interleaved 16-row blocks 2f+wm)
    const int wn = wave & 3;                // 0..3  (N, contiguous 64-col stripe)
    const int q = lane >> 4, r = lane & 15;

    // staging source offsets (ushort units) per (half, ii): slot s = h*1024+ii*512+tid
    // holds logical chunk ((s&7)-row)&7 of row s>>3 (inverse of the read swizzle).
    size_t aoff[2][2], boff[2][2];
    #pragma unroll
    for (int h = 0; h < 2; ++h)
        #pragma unroll
        for (int ii = 0; ii < 2; ++ii) {
            const int s   = h * 1024 + ii * 512 + tid;
            const int row = s >> 3;
            const int cg  = ((s & 7) - row) & 7;
            aoff[h][ii] = (size_t)(brow0 + row) * KT + cg * 8;
            boff[h][ii] = (size_t)(bcol0 + row) * KT + cg * 8;
        }

#define GLDS(srcp, dstp)                                                            \
    __builtin_amdgcn_global_load_lds(                                               \
        (const __attribute__((address_space(1))) unsigned int*)(srcp),              \
        (__attribute__((address_space(3))) unsigned int*)(dstp), 16, 0, 0)

    auto stageA = [&](int tile, int h) {
        const int buf = tile & 1;
        const size_t k = (size_t)tile * BK;
        GLDS(Abf + aoff[h][0] + k, As + buf * 16384 + (h * 1024 + wave * 64) * 8);
        GLDS(Abf + aoff[h][1] + k, As + buf * 16384 + (h * 1024 + 512 + wave * 64) * 8);
    };
    auto stageB = [&](int tile, int h) {
        const int buf = tile & 1;
        const size_t k = (size_t)tile * BK;
        GLDS(Bbf + boff[h][0] + k, Bs + buf * 16384 + (h * 1024 + wave * 64) * 8);
        GLDS(Bbf + boff[h][1] + k, Bs + buf * 16384 + (h * 1024 + 512 + wave * 64) * 8);
    };

    f32x4 acc[8][4] = {};
    short8 a[2][2];   // [u][kh] current phase's 2 M-frags
    short8 b[4][2];   // [j][kh] whole K-tile's B frags (read at phase 1, held 4 phases)

    auto ldA = [&](int buf, int p) {
        const unsigned short* base = As + buf * 16384;
        #pragma unroll
        for (int u = 0; u < 2; ++u) {
            const int row = (4 * p + 2 * u + wm) * 16 + r;
            #pragma unroll
            for (int kh = 0; kh < 2; ++kh)
                a[u][kh] = *(const short8*)(base + row * 64 + ((kh * 4 + q + row) & 7) * 8);
        }
    };
    auto ldB = [&](int buf) {
        const unsigned short* base = Bs + buf * 16384;
        #pragma unroll
        for (int j = 0; j < 4; ++j) {
            const int row = (4 * wn + j) * 16 + r;
            #pragma unroll
            for (int kh = 0; kh < 2; ++kh)
                b[j][kh] = *(const short8*)(base + row * 64 + ((kh * 4 + q + row) & 7) * 8);
        }
    };
    auto mma = [&](int p) {
        #pragma unroll
        for (int kh = 0; kh < 2; ++kh)
            #pragma unroll
            for (int u = 0; u < 2; ++u)
                #pragma unroll
                for (int j = 0; j < 4; ++j)
                    acc[2 * p + u][j] = __builtin_amdgcn_mfma_f32_16x16x32_bf16(
                        a[u][kh], b[j][kh], acc[2 * p + u][j], 0, 0, 0);
    };

#define PHASE(buf, p, STAGE_STMT, WAIT_STMT) do {          \
        ldA(buf, p);                                       \
        if ((p) == 0) ldB(buf);                            \
        STAGE_STMT;                                        \
        __builtin_amdgcn_s_barrier();                      \
        asm volatile("s_waitcnt lgkmcnt(0)");              \
        __builtin_amdgcn_sched_barrier(0);                 \
        __builtin_amdgcn_s_setprio(1);                     \
        mma(p);                                            \
        __builtin_amdgcn_s_setprio(0);                     \
        WAIT_STMT;                                         \
        __builtin_amdgcn_s_barrier();                      \
    } while (0)

    // prologue: tile0 fully + 3/4 of tile1; vmcnt(6) leaves tile1's 3 halves in
    // flight, guarantees tile0 landed; barrier publishes across waves.
    stageB(0, 0); stageB(0, 1); stageA(0, 0); stageA(0, 1);
    asm volatile("s_waitcnt vmcnt(4)" ::: "memory");
    stageB(1, 0); stageA(1, 0); stageB(1, 1);
    asm volatile("s_waitcnt vmcnt(6)" ::: "memory");
    __builtin_amdgcn_s_barrier();

    #pragma unroll 1
    for (int i = 0; i < NKT / 2 - 1; ++i) {        // 15 iterations: tiles 0..29
        const int t1 = 2 * i + 1, t2 = 2 * i + 2, t3 = 2 * i + 3;
        PHASE(0, 0, stageA(t1, 1), (void)0);
        PHASE(0, 1, stageB(t2, 0), (void)0);
        PHASE(0, 2, stageA(t2, 0), (void)0);
        PHASE(0, 3, stageB(t2, 1), asm volatile("s_waitcnt vmcnt(6)" ::: "memory"));
        PHASE(1, 0, stageA(t2, 1), (void)0);
        PHASE(1, 1, stageB(t3, 0), (void)0);
        PHASE(1, 2, stageA(t3, 0), (void)0);
        PHASE(1, 3, stageB(t3, 1), asm volatile("s_waitcnt vmcnt(6)" ::: "memory"));
    }

    // epilogue iteration: tiles 30 (buf0), 31 (buf1); drain 4 -> 2 -> 0
    PHASE(0, 0, stageA(NKT - 1, 1), (void)0);
    PHASE(0, 1, (void)0, asm volatile("s_waitcnt vmcnt(4)" ::: "memory"));
    PHASE(0, 2, (void)0, asm volatile("s_waitcnt vmcnt(2)" ::: "memory"));
    PHASE(0, 3, (void)0, asm volatile("s_waitcnt vmcnt(0)" ::: "memory"));
    PHASE(1, 0, (void)0, (void)0);
    PHASE(1, 1, (void)0, (void)0);
    PHASE(1, 2, (void)0, (void)0);
    PHASE(1, 3, (void)0, (void)0);

#undef PHASE
#undef GLDS

    // epilogue: C/D layout col = lane&15, row = (lane>>4)*4 + reg  [m89/m91-verified]
    // f-th M-frag sits at global 16-row block (2f + wm)  (interleaved mapping)
    #pragma unroll
    for (int j = 0; j < 4; ++j) {
        const int n  = bcol0 + (4 * wn + j) * 16 + r;
        const float sc = ldexpf(1.0f, sexp[n]);   // exact power-of-two scale
        const float bs = bias[n];
        #pragma unroll
        for (int f = 0; f < 8; ++f) {
            const int m = brow0 + (2 * f + wm) * 16 + q * 4;
            float* cp = C + (size_t)m * NT + n;
            #pragma unroll
            for (int t = 0; t < 4; ++t)
                cp[(size_t)t * NT] = acc[f][j][t] * sc + bs;
        }
    }
}

// ---- fallback (no workspace): old verified fused 128x128 kernel ----

__device__ __forceinline__ int swzf(int row, int c) { return row * 8 + ((c + row) & 7); }

__global__ __launch_bounds__(256) void gemm_fb(
    const float* __restrict__ Af32, const int* __restrict__ Wi32,
    const int* __restrict__ sexp, const float* __restrict__ bias,
    float* __restrict__ C)
{
    __shared__ unsigned short As[128 * 64];
    __shared__ unsigned short Bs[128 * 64];

    const int tid  = threadIdx.x;
    const int row0 = blockIdx.y * 128;
    const int col0 = blockIdx.x * 128;
    const int lane = tid & 63;
    const int wave = tid >> 6;
    const int wm = wave >> 1, wn = wave & 1;
    const int q = lane >> 4, r = lane & 15;

    f32x4 acc[4][4] = {};

    for (int k0 = 0; k0 < KT; k0 += 64) {
        #pragma unroll
        for (int ii = 0; ii < 8; ++ii) {
            const int s  = tid + ii * 256;
            const int rw = s >> 4, c4 = s & 15;
            const int ch = c4 >> 1, hf = c4 & 1;
            const int ps = ((ch + rw) & 7) * 8 + hf * 4;
            float4 v = *(const float4*)(Af32 + (size_t)(row0 + rw) * KT + k0 + c4 * 4);
            ushort4v oa;
            oa[0] = f32_bf16(v.x); oa[1] = f32_bf16(v.y);
            oa[2] = f32_bf16(v.z); oa[3] = f32_bf16(v.w);
            *(ushort4v*)(As + rw * 64 + ps) = oa;
            int4 w4 = *(const int4*)(Wi32 + (size_t)(col0 + rw) * KT + k0 + c4 * 4);
            ushort4v ob;
            ob[0] = f32_bf16((float)w4.x); ob[1] = f32_bf16((float)w4.y);
            ob[2] = f32_bf16((float)w4.z); ob[3] = f32_bf16((float)w4.w);
            *(ushort4v*)(Bs + rw * 64 + ps) = ob;
        }
        __syncthreads();
        #pragma unroll
        for (int h = 0; h < 2; ++h) {
            short8 a[4], b[4];
            #pragma unroll
            for (int i = 0; i < 4; ++i)
                a[i] = *(const short8*)(As + swzf(wm * 64 + i * 16 + r, h * 4 + q) * 8);
            #pragma unroll
            for (int j = 0; j < 4; ++j)
                b[j] = *(const short8*)(Bs + swzf(wn * 64 + j * 16 + r, h * 4 + q) * 8);
            #pragma unroll
            for (int i = 0; i < 4; ++i)
                #pragma unroll
                for (int j = 0; j < 4; ++j)
                    acc[i][j] = __builtin_amdgcn_mfma_f32_16x16x32_bf16(a[i], b[j], acc[i][j], 0, 0, 0);
        }
        __syncthreads();
    }

    #pragma unroll
    for (int j = 0; j < 4; ++j) {
        const int n  = col0 + wn * 64 + j * 16 + r;
        const float sc = ldexpf(1.0f, sexp[n]);
        const float bs = bias[n];
        #pragma unroll
        for (int i = 0; i < 4; ++i) {
            const int m = row0 + wm * 64 + i * 16 + q * 4;
            float* cp = C + (size_t)m * NT + n;
            #pragma unroll
            for (int t = 0; t < 4; ++t)
                cp[(size_t)t * NT] = acc[i][j][t] * sc + bs;
        }
    }
}

extern "C" void kernel_launch(void* const* d_in, const int* in_sizes, int n_in,
                              void* d_out, int out_size, void* d_ws, size_t ws_size,
                              hipStream_t stream) {
    const float* x    = (const float*)d_in[0];
    const int*   wq   = (const int*)d_in[1];   // ternary {-1,0,1}, int32 per harness
    const int*   se   = (const int*)d_in[2];   // exponents [-8,0]
    const float* bias = (const float*)d_in[3];
    float* out = (float*)d_out;

    const size_t xb_elems = (size_t)MT * KT;   // 33554432
    const size_t wb_elems = (size_t)NT * KT;   // 4194304

    if (ws_size >= (xb_elems + wb_elems) * sizeof(unsigned short)) {
        unsigned short* xb = (unsigned short*)d_ws;
        unsigned short* wb = xb + xb_elems;
        cvt_kernel<<<(int)((xb_elems + wb_elems) / (256 * 8)), 256, 0, stream>>>(x, wq, xb, wb);
        dim3 grid(NT / BN, MT / BM);           // (8, 64): bn fast == XCD id, B-slab L2-resident
        gemm_8ph<<<grid, THREADS, 0, stream>>>(xb, wb, se, bias, out);
    } else {
        dim3 fgrid(NT / 128, MT / 128);        // (16, 128)
        gemm_fb<<<fgrid, 256, 0, stream>>>(x, wq, se, bias, out);
    }
}